// Round 2
// baseline (1286.083 us; speedup 1.0000x reference)
//
#include <hip/hip_runtime.h>
#include <hip/hip_bf16.h>

#define BB 8192
#define TT 8
#define DEe 512
#define DRr 1024
#define HH 1024
#define KG 1536      // 512 + 1024 (ent|rel)
#define MG 65536     // B*T rows of the time-parallel projection

typedef __attribute__((ext_vector_type(8))) __bf16 bf16x8;
typedef __attribute__((ext_vector_type(4))) __bf16 bf16x4;
typedef __attribute__((ext_vector_type(4))) float f32x4;

__device__ __forceinline__ void gld_lds16(const __bf16* g, __bf16* l) {
    __builtin_amdgcn_global_load_lds(
        (const __attribute__((address_space(1))) void*)g,
        (__attribute__((address_space(3))) void*)l, 16, 0, 0);
}

// GA[m][0:1536] = [ent_flat[m] | rel_flat[m]] as bf16, m = b*T + t (matches out rows).
// grid-stride over float4 groups: 65536 * 384 f4s.
__global__ void pack_ga(const float* __restrict__ ent, const float* __restrict__ rel,
                        __bf16* __restrict__ ga) {
    const int total = MG * (KG / 4);             // 25,165,824
    const int stride = gridDim.x * blockDim.x;
    for (int g = blockIdx.x * blockDim.x + threadIdx.x; g < total; g += stride) {
        int m = g / 384;
        int c4 = g - m * 384;
        float4 v;
        if (c4 < 128) v = ((const float4*)ent)[(size_t)m * 128 + c4];
        else          v = ((const float4*)rel)[(size_t)m * 256 + (c4 - 128)];
        bf16x4 o = {(__bf16)v.x, (__bf16)v.y, (__bf16)v.z, (__bf16)v.w};
        *(bf16x4*)(ga + (size_t)m * KG + c4 * 4) = o;
    }
}

// BW [1024 x 1536] = [We | Wr] rows bf16; WhP [1024 x 1024] = Wh bf16.
// grid (5, 1024), block 128.
__global__ void pack_bw(const float* __restrict__ We, const float* __restrict__ Wr,
                        const float* __restrict__ Wh,
                        __bf16* __restrict__ BW, __bf16* __restrict__ WhP) {
    const int n = blockIdx.y;
    const int sec = blockIdx.x;
    const int i = threadIdx.x;
    float4 v; __bf16* dst;
    if (sec == 0) {
        v = *(const float4*)(We + (size_t)n * DEe + i * 4);
        dst = BW + (size_t)n * KG + i * 4;
    } else if (sec <= 2) {
        int d = (sec - 1) * 512 + i * 4;
        v = *(const float4*)(Wr + (size_t)n * DRr + d);
        dst = BW + (size_t)n * KG + DEe + d;
    } else {
        int d = (sec - 3) * 512 + i * 4;
        v = *(const float4*)(Wh + (size_t)n * HH + d);
        dst = WhP + (size_t)n * HH + d;
    }
    bf16x4 o = {(__bf16)v.x, (__bf16)v.y, (__bf16)v.z, (__bf16)v.w};
    *(bf16x4*)dst = o;
}

// Big time-parallel GEMM: g[65536,1024] = GA @ BW^T + (be+br+bh).
// Writes pre-activation g into out[m][n]; rows with t==0 get relu + h0 (bf16).
// m97 structure: 128x128 tile, BK=32, 4 waves, 16x16x32 bf16 MFMA, gld_lds w16.
// grid (8, 512) = 4096 blocks, XCD-swizzled so each XCD owns a contiguous M-range.
__global__ __launch_bounds__(256) void gemm_g(
    const __bf16* __restrict__ A, const __bf16* __restrict__ Bw,
    const float* __restrict__ be, const float* __restrict__ br,
    const float* __restrict__ bh,
    float* __restrict__ out, __bf16* __restrict__ h0) {
    __shared__ __bf16 sA[128 * 32];
    __shared__ __bf16 sB[128 * 32];
    __shared__ float sBias[128];

    const int tid  = threadIdx.x;
    const int lane = tid & 63;
    const int w    = tid >> 6;
    const int bid  = blockIdx.y * 8 + blockIdx.x;       // 4096, %8==0 ok
    const int swz  = (bid & 7) * 512 + (bid >> 3);      // bijective XCD swizzle
    const int tileN = (swz & 7) * 128;
    const int tileM = (swz >> 3) * 128;

    if (tid < 128) {
        int n = tileN + tid;
        sBias[tid] = be[n] + br[n] + bh[n];
    }

    const int r0 = (w * 2 + 0) * 16 + (lane >> 2);
    const int r1 = (w * 2 + 1) * 16 + (lane >> 2);
    const int cc = (lane & 3) * 8;
    const __bf16* gA0 = A + (size_t)(tileM + r0) * KG + cc;
    const __bf16* gA1 = A + (size_t)(tileM + r1) * KG + cc;
    const __bf16* gB0 = Bw + (size_t)(tileN + r0) * KG + cc;
    const __bf16* gB1 = Bw + (size_t)(tileN + r1) * KG + cc;
    __bf16* lA0 = sA + (w * 2 + 0) * 512;
    __bf16* lA1 = sA + (w * 2 + 1) * 512;
    __bf16* lB0 = sB + (w * 2 + 0) * 512;
    __bf16* lB1 = sB + (w * 2 + 1) * 512;

    const int wm = (w >> 1) * 64, wn = (w & 1) * 64;
    const int fm = lane & 15, fq = lane >> 4;

    f32x4 acc[4][4];
#pragma unroll
    for (int i = 0; i < 4; i++)
#pragma unroll
        for (int j = 0; j < 4; j++) acc[i][j] = {0.f, 0.f, 0.f, 0.f};

    for (int k0 = 0; k0 < KG; k0 += 32) {
        gld_lds16(gA0 + k0, lA0);
        gld_lds16(gA1 + k0, lA1);
        gld_lds16(gB0 + k0, lB0);
        gld_lds16(gB1 + k0, lB1);
        __syncthreads();
        bf16x8 af[4], bf[4];
#pragma unroll
        for (int mf = 0; mf < 4; mf++)
            af[mf] = *(const bf16x8*)&sA[(wm + mf * 16 + fm) * 32 + fq * 8];
#pragma unroll
        for (int nf = 0; nf < 4; nf++)
            bf[nf] = *(const bf16x8*)&sB[(wn + nf * 16 + fm) * 32 + fq * 8];
#pragma unroll
        for (int mf = 0; mf < 4; mf++)
#pragma unroll
            for (int nf = 0; nf < 4; nf++)
                acc[mf][nf] = __builtin_amdgcn_mfma_f32_16x16x32_bf16(
                    af[mf], bf[nf], acc[mf][nf], 0, 0, 0);
        __syncthreads();
    }

    // C/D layout: col = lane&15, row = (lane>>4)*4 + reg
#pragma unroll
    for (int mf = 0; mf < 4; mf++) {
#pragma unroll
        for (int nf = 0; nf < 4; nf++) {
            f32x4 v = acc[mf][nf];
            const int nl = wn + nf * 16 + fm;
            const int n  = tileN + nl;
            const int m0 = tileM + wm + mf * 16 + fq * 4;
            const float bias = sBias[nl];
            const bool t0row = ((m0 & 7) == 0);   // r==0 row has t==0
#pragma unroll
            for (int r = 0; r < 4; r++) {
                float x = v[r] + bias;
                size_t m = (size_t)(m0 + r);
                if (t0row && r == 0) {
                    float hv = x > 0.f ? x : 0.f;
                    out[m * HH + n] = hv;                    // relu'd final out_0
                    h0[(m >> 3) * HH + n] = (__bf16)hv;      // h after t=0
                } else {
                    out[m * HH + n] = x;                     // pre-activation g_t
                }
            }
        }
    }
}

// Recurrence step t>=1: h_t = relu(g_t + h_{t-1} @ Wh^T), g_t read from out,
// relu'd value written back to out; hn gets bf16 h_t; t==7 also writes need[n][b].
// M=8192, N=1024, K=1024. grid (8, 64) = 512 blocks.
__global__ __launch_bounds__(256) void gemm_step(
    const __bf16* __restrict__ A, const __bf16* __restrict__ Bw,
    float* __restrict__ out, __bf16* __restrict__ hn,
    float* __restrict__ need, int t) {
    __shared__ __bf16 sA[128 * 32];
    __shared__ __bf16 sB[128 * 32];

    const int tid  = threadIdx.x;
    const int lane = tid & 63;
    const int w    = tid >> 6;
    const int bid  = blockIdx.y * 8 + blockIdx.x;     // 512
    const int swz  = (bid & 7) * 64 + (bid >> 3);
    const int tileN = (swz & 7) * 128;
    const int tileM = (swz >> 3) * 128;

    const int r0 = (w * 2 + 0) * 16 + (lane >> 2);
    const int r1 = (w * 2 + 1) * 16 + (lane >> 2);
    const int cc = (lane & 3) * 8;
    const __bf16* gA0 = A + (size_t)(tileM + r0) * HH + cc;
    const __bf16* gA1 = A + (size_t)(tileM + r1) * HH + cc;
    const __bf16* gB0 = Bw + (size_t)(tileN + r0) * HH + cc;
    const __bf16* gB1 = Bw + (size_t)(tileN + r1) * HH + cc;
    __bf16* lA0 = sA + (w * 2 + 0) * 512;
    __bf16* lA1 = sA + (w * 2 + 1) * 512;
    __bf16* lB0 = sB + (w * 2 + 0) * 512;
    __bf16* lB1 = sB + (w * 2 + 1) * 512;

    const int wm = (w >> 1) * 64, wn = (w & 1) * 64;
    const int fm = lane & 15, fq = lane >> 4;

    f32x4 acc[4][4];
#pragma unroll
    for (int i = 0; i < 4; i++)
#pragma unroll
        for (int j = 0; j < 4; j++) acc[i][j] = {0.f, 0.f, 0.f, 0.f};

    for (int k0 = 0; k0 < HH; k0 += 32) {
        gld_lds16(gA0 + k0, lA0);
        gld_lds16(gA1 + k0, lA1);
        gld_lds16(gB0 + k0, lB0);
        gld_lds16(gB1 + k0, lB1);
        __syncthreads();
        bf16x8 af[4], bf[4];
#pragma unroll
        for (int mf = 0; mf < 4; mf++)
            af[mf] = *(const bf16x8*)&sA[(wm + mf * 16 + fm) * 32 + fq * 8];
#pragma unroll
        for (int nf = 0; nf < 4; nf++)
            bf[nf] = *(const bf16x8*)&sB[(wn + nf * 16 + fm) * 32 + fq * 8];
#pragma unroll
        for (int mf = 0; mf < 4; mf++)
#pragma unroll
            for (int nf = 0; nf < 4; nf++)
                acc[mf][nf] = __builtin_amdgcn_mfma_f32_16x16x32_bf16(
                    af[mf], bf[nf], acc[mf][nf], 0, 0, 0);
        __syncthreads();
    }

#pragma unroll
    for (int mf = 0; mf < 4; mf++) {
#pragma unroll
        for (int nf = 0; nf < 4; nf++) {
            f32x4 v = acc[mf][nf];
            const int nl = wn + nf * 16 + fm;
            const int n  = tileN + nl;
            const int m0 = tileM + wm + mf * 16 + fq * 4;
            float hv[4];
#pragma unroll
            for (int r = 0; r < 4; r++) {
                size_t addr = ((size_t)(m0 + r) * TT + t) * HH + n;
                float x = v[r] + out[addr];          // + g_t (pre-activation)
                hv[r] = x > 0.f ? x : 0.f;
                out[addr] = hv[r];
                if (hn) hn[(size_t)(m0 + r) * HH + n] = (__bf16)hv[r];
            }
            if (need) {
                f32x4 nv = {hv[0], hv[1], hv[2], hv[3]};
                *(f32x4*)&need[(size_t)n * BB + m0] = nv;
            }
        }
    }
}

extern "C" void kernel_launch(void* const* d_in, const int* in_sizes, int n_in,
                              void* d_out, int out_size, void* d_ws, size_t ws_size,
                              hipStream_t stream) {
    const float* ent = (const float*)d_in[0];
    const float* rel = (const float*)d_in[1];
    const float* We  = (const float*)d_in[2];
    const float* be  = (const float*)d_in[3];
    const float* Wr  = (const float*)d_in[4];
    const float* br  = (const float*)d_in[5];
    const float* Wh  = (const float*)d_in[6];
    const float* bh  = (const float*)d_in[7];

    float* out  = (float*)d_out;
    float* need = out + (size_t)BB * TT * HH;   // [H, B] region

    // workspace: GA 201.3MB | BW 3.1MB | WhP 2.1MB | hA 16.8MB | hB 16.8MB (~240MB)
    char* ws = (char*)d_ws;
    __bf16* GA  = (__bf16*)ws;
    __bf16* BW  = (__bf16*)(ws + (size_t)MG * KG * 2);
    __bf16* WhP = (__bf16*)(ws + (size_t)MG * KG * 2 + (size_t)HH * KG * 2);
    __bf16* hA  = (__bf16*)((char*)WhP + (size_t)HH * HH * 2);
    __bf16* hB  = (__bf16*)((char*)hA + (size_t)BB * HH * 2);
    __bf16* hbuf[2] = {hA, hB};

    pack_bw<<<dim3(5, 1024), 128, 0, stream>>>(We, Wr, Wh, BW, WhP);
    pack_ga<<<dim3(2048), 256, 0, stream>>>(ent, rel, GA);
    gemm_g<<<dim3(8, 512), 256, 0, stream>>>(GA, BW, be, br, bh, out, hA);
    for (int t = 1; t < TT; t++) {
        gemm_step<<<dim3(8, 64), 256, 0, stream>>>(
            hbuf[(t - 1) & 1], WhP, out,
            (t < 7) ? hbuf[t & 1] : nullptr,
            (t == 7) ? need : nullptr, t);
    }
}

// Round 6
// 1209.189 us; speedup vs baseline: 1.0636x; 1.0636x over previous
//
#include <hip/hip_runtime.h>
#include <hip/hip_bf16.h>

#define BB 8192
#define TT 8
#define DEe 512
#define DRr 1024
#define HH 1024
#define KG 1536      // 512 + 1024 (ent|rel)
#define MG 65536     // B*T rows of the time-parallel projection

typedef __attribute__((ext_vector_type(8))) __bf16 bf16x8;
typedef __attribute__((ext_vector_type(4))) __bf16 bf16x4;
typedef __attribute__((ext_vector_type(4))) float f32x4;

__device__ __forceinline__ void gld_lds16(const __bf16* g, __bf16* l) {
    __builtin_amdgcn_global_load_lds(
        (const __attribute__((address_space(1))) void*)g,
        (__attribute__((address_space(3))) void*)l, 16, 0, 0);
}

// GA[m][0:1536] = [ent_flat[m] | rel_flat[m]] as bf16, m = b*T + t.
__global__ void pack_ga(const float* __restrict__ ent, const float* __restrict__ rel,
                        __bf16* __restrict__ ga) {
    const int total = MG * (KG / 4);             // 25,165,824
    const int stride = gridDim.x * blockDim.x;
    for (int g = blockIdx.x * blockDim.x + threadIdx.x; g < total; g += stride) {
        int m = g / 384;
        int c4 = g - m * 384;
        float4 v;
        if (c4 < 128) v = ((const float4*)ent)[(size_t)m * 128 + c4];
        else          v = ((const float4*)rel)[(size_t)m * 256 + (c4 - 128)];
        bf16x4 o = {(__bf16)v.x, (__bf16)v.y, (__bf16)v.z, (__bf16)v.w};
        *(bf16x4*)(ga + (size_t)m * KG + c4 * 4) = o;
    }
}

// BW [1024 x 1536] = [We | Wr] rows bf16 (row-major, for gemm_g).
// WhT = Wh packed into K-tiles for rnn_local: element (n,k) ->
//   (k>>5)*32768 + ((k>>3)&3)*8192 + n*8 + (k&7)   (bf16 units)
// => each 64KB k-tile contiguous; B-frag reads 16B contiguous per lane.
__global__ void pack_bw(const float* __restrict__ We, const float* __restrict__ Wr,
                        const float* __restrict__ Wh,
                        __bf16* __restrict__ BW, __bf16* __restrict__ WhT) {
    const int n = blockIdx.y;
    const int sec = blockIdx.x;
    const int i = threadIdx.x;
    float4 v; __bf16* dst;
    if (sec == 0) {
        v = *(const float4*)(We + (size_t)n * DEe + i * 4);
        dst = BW + (size_t)n * KG + i * 4;
    } else if (sec <= 2) {
        int d = (sec - 1) * 512 + i * 4;
        v = *(const float4*)(Wr + (size_t)n * DRr + d);
        dst = BW + (size_t)n * KG + DEe + d;
    } else {
        int d = (sec - 3) * 512 + i * 4;   // k, multiple of 4
        v = *(const float4*)(Wh + (size_t)n * HH + d);
        dst = WhT + (d >> 5) * 32768 + ((d >> 3) & 3) * 8192 + n * 8 + (d & 7);
    }
    bf16x4 o = {(__bf16)v.x, (__bf16)v.y, (__bf16)v.z, (__bf16)v.w};
    *(bf16x4*)dst = o;
}

// Big time-parallel GEMM: g[65536,1024] = GA @ BW^T + (be+br+bh).
// Writes pre-activation g into out; rows with t==0 get relu (they ARE h0).
// (unchanged; proven passing in round 2)
__global__ __launch_bounds__(256) void gemm_g(
    const __bf16* __restrict__ A, const __bf16* __restrict__ Bw,
    const float* __restrict__ be, const float* __restrict__ br,
    const float* __restrict__ bh, float* __restrict__ out) {
    __shared__ __bf16 sA[128 * 32];
    __shared__ __bf16 sB[128 * 32];
    __shared__ float sBias[128];

    const int tid  = threadIdx.x;
    const int lane = tid & 63;
    const int w    = tid >> 6;
    const int bid  = blockIdx.y * 8 + blockIdx.x;
    const int swz  = (bid & 7) * 512 + (bid >> 3);
    const int tileN = (swz & 7) * 128;
    const int tileM = (swz >> 3) * 128;

    if (tid < 128) {
        int n = tileN + tid;
        sBias[tid] = be[n] + br[n] + bh[n];
    }

    const int r0 = (w * 2 + 0) * 16 + (lane >> 2);
    const int r1 = (w * 2 + 1) * 16 + (lane >> 2);
    const int cc = (lane & 3) * 8;
    const __bf16* gA0 = A + (size_t)(tileM + r0) * KG + cc;
    const __bf16* gA1 = A + (size_t)(tileM + r1) * KG + cc;
    const __bf16* gB0 = Bw + (size_t)(tileN + r0) * KG + cc;
    const __bf16* gB1 = Bw + (size_t)(tileN + r1) * KG + cc;
    __bf16* lA0 = sA + (w * 2 + 0) * 512;
    __bf16* lA1 = sA + (w * 2 + 1) * 512;
    __bf16* lB0 = sB + (w * 2 + 0) * 512;
    __bf16* lB1 = sB + (w * 2 + 1) * 512;

    const int wm = (w >> 1) * 64, wn = (w & 1) * 64;
    const int fm = lane & 15, fq = lane >> 4;

    f32x4 acc[4][4];
#pragma unroll
    for (int i = 0; i < 4; i++)
#pragma unroll
        for (int j = 0; j < 4; j++) acc[i][j] = {0.f, 0.f, 0.f, 0.f};

    for (int k0 = 0; k0 < KG; k0 += 32) {
        gld_lds16(gA0 + k0, lA0);
        gld_lds16(gA1 + k0, lA1);
        gld_lds16(gB0 + k0, lB0);
        gld_lds16(gB1 + k0, lB1);
        __syncthreads();
        bf16x8 af[4], bfv[4];
#pragma unroll
        for (int mf = 0; mf < 4; mf++)
            af[mf] = *(const bf16x8*)&sA[(wm + mf * 16 + fm) * 32 + fq * 8];
#pragma unroll
        for (int nf = 0; nf < 4; nf++)
            bfv[nf] = *(const bf16x8*)&sB[(wn + nf * 16 + fm) * 32 + fq * 8];
#pragma unroll
        for (int mf = 0; mf < 4; mf++)
#pragma unroll
            for (int nf = 0; nf < 4; nf++)
                acc[mf][nf] = __builtin_amdgcn_mfma_f32_16x16x32_bf16(
                    af[mf], bfv[nf], acc[mf][nf], 0, 0, 0);
        __syncthreads();
    }

#pragma unroll
    for (int mf = 0; mf < 4; mf++) {
#pragma unroll
        for (int nf = 0; nf < 4; nf++) {
            f32x4 v = acc[mf][nf];
            const int nl = wn + nf * 16 + fm;
            const int n  = tileN + nl;
            const int m0 = tileM + wm + mf * 16 + fq * 4;
            const float bias = sBias[nl];
            const bool t0row = ((m0 & 7) == 0);
#pragma unroll
            for (int r = 0; r < 4; r++) {
                float x = v[r] + bias;
                size_t m = (size_t)(m0 + r);
                if (t0row && r == 0) {
                    out[m * HH + n] = x > 0.f ? x : 0.f;   // relu'd h0 = out_0
                } else {
                    out[m * HH + n] = x;                   // pre-activation g_t
                }
            }
        }
    }
}

// All 7 recurrence steps, BLOCK-LOCAL: each block owns 32 batch rows for the
// whole recurrence. h lives in LDS (bf16, XOR-swizzled byte^=(m&7)<<4); Wh
// streams through a 64KB LDS tile per K-step. No grid sync, no atomics.
// Wh staging is REG-STAGED (global->reg->ds_write), NOT global_load_lds:
// sB sits at LDS offset 64KB, and global_load_lds to >64KB LDS offsets is
// unproven on this HW (suspected cause of the round-4/5 container hangs).
// 256 blocks x 512 threads (8 waves; wave w owns N-cols [w*128, w*128+128)).
__global__ __launch_bounds__(512, 1) void rnn_local(
    const __bf16* __restrict__ Bw,   // WhT packed
    float* __restrict__ out, float* __restrict__ need) {
    __shared__ __bf16 sH[32 * 1024];   // 64KB: h rows, swizzled
    __shared__ __bf16 sB[32 * 1024];   // 64KB: one K-tile of WhT

    const int tid  = threadIdx.x;
    const int lane = tid & 63;
    const int w    = tid >> 6;          // 0..7
    const int b0   = blockIdx.x * 32;
    const int fm   = lane & 15, fq = lane >> 4;
    const int wn   = w * 128;

    // init: h0 = out[b][0][:] (already relu'd by gemm_g) -> sH bf16 swizzled
#pragma unroll
    for (int i = 0; i < 8; i++) {
        int c  = i * 512 + tid;          // 4096 chunks of 8 cols
        int m  = c >> 7;                 // 0..31
        int cc = (c & 127) * 8;
        const float* src = out + ((size_t)(b0 + m) * TT + 0) * HH + cc;
        float4 v0 = *(const float4*)src;
        float4 v1 = *(const float4*)(src + 4);
        bf16x8 o = {(__bf16)v0.x, (__bf16)v0.y, (__bf16)v0.z, (__bf16)v0.w,
                    (__bf16)v1.x, (__bf16)v1.y, (__bf16)v1.z, (__bf16)v1.w};
        int byte = (m * 2048 + cc * 2) ^ ((m & 7) << 4);
        *(bf16x8*)((char*)sH + byte) = o;
    }
    __syncthreads();

    for (int t = 1; t < TT; t++) {
        f32x4 acc[2][8];
#pragma unroll
        for (int i = 0; i < 2; i++)
#pragma unroll
            for (int j = 0; j < 8; j++) acc[i][j] = {0.f, 0.f, 0.f, 0.f};

        for (int k0i = 0; k0i < 32; k0i++) {
            // stage 64KB K-tile, reg-staged: 8x16B per thread, loads first
            const __bf16* gsrc = Bw + (size_t)k0i * 32768;
            float4 stg[8];
#pragma unroll
            for (int j = 0; j < 8; j++)
                stg[j] = *(const float4*)(gsrc + ((size_t)(j * 512 + tid)) * 8);
#pragma unroll
            for (int j = 0; j < 8; j++)
                *(float4*)(sB + (size_t)(j * 512 + tid) * 8) = stg[j];
            __syncthreads();   // tile ready

            bf16x8 af[2], bfv[8];
            const int kb = k0i * 64;   // byte offset of k0 within an h row
#pragma unroll
            for (int mf = 0; mf < 2; mf++) {
                int m = mf * 16 + fm;
                int byte = (m * 2048 + kb + fq * 16) ^ ((m & 7) << 4);
                af[mf] = *(const bf16x8*)((const char*)sH + byte);
            }
#pragma unroll
            for (int nf = 0; nf < 8; nf++) {
                int n = wn + nf * 16 + fm;
                bfv[nf] = *(const bf16x8*)((const char*)sB + (fq * 1024 + n) * 16);
            }
#pragma unroll
            for (int mf = 0; mf < 2; mf++)
#pragma unroll
                for (int nf = 0; nf < 8; nf++)
                    acc[mf][nf] = __builtin_amdgcn_mfma_f32_16x16x32_bf16(
                        af[mf], bfv[nf], acc[mf][nf], 0, 0, 0);
            __syncthreads();   // sB reuse next iter; also fences sH reads
        }

        // epilogue: x = acc + g_t (from out), relu -> out, bf16 -> sH (in place)
#pragma unroll
        for (int mf = 0; mf < 2; mf++) {
#pragma unroll
            for (int nf = 0; nf < 8; nf++) {
                f32x4 v = acc[mf][nf];
                const int n  = wn + nf * 16 + fm;
                const int m0 = mf * 16 + fq * 4;
                float hv[4];
#pragma unroll
                for (int r = 0; r < 4; r++) {
                    int m = m0 + r;
                    size_t addr = ((size_t)(b0 + m) * TT + t) * HH + n;
                    float x = v[r] + out[addr];
                    hv[r] = x > 0.f ? x : 0.f;
                    out[addr] = hv[r];
                    int byte = (m * 2048 + n * 2) ^ ((m & 7) << 4);
                    *(__bf16*)((char*)sH + byte) = (__bf16)hv[r];
                }
                if (t == 7) {
                    f32x4 nv = {hv[0], hv[1], hv[2], hv[3]};
                    *(f32x4*)&need[(size_t)n * BB + b0 + m0] = nv;
                }
            }
        }
        __syncthreads();   // h_t fully written before next step's A-reads
    }
}

extern "C" void kernel_launch(void* const* d_in, const int* in_sizes, int n_in,
                              void* d_out, int out_size, void* d_ws, size_t ws_size,
                              hipStream_t stream) {
    const float* ent = (const float*)d_in[0];
    const float* rel = (const float*)d_in[1];
    const float* We  = (const float*)d_in[2];
    const float* be  = (const float*)d_in[3];
    const float* Wr  = (const float*)d_in[4];
    const float* br  = (const float*)d_in[5];
    const float* Wh  = (const float*)d_in[6];
    const float* bh  = (const float*)d_in[7];

    float* out  = (float*)d_out;
    float* need = out + (size_t)BB * TT * HH;   // [H, B] region

    // workspace: GA 201.3MB | BW 3.1MB | WhT 2.1MB
    char* ws = (char*)d_ws;
    __bf16* GA  = (__bf16*)ws;
    __bf16* BW  = (__bf16*)(ws + (size_t)MG * KG * 2);
    __bf16* WhT = (__bf16*)(ws + (size_t)MG * KG * 2 + (size_t)HH * KG * 2);

    pack_bw<<<dim3(5, 1024), 128, 0, stream>>>(We, Wr, Wh, BW, WhT);
    pack_ga<<<dim3(2048), 256, 0, stream>>>(ent, rel, GA);
    gemm_g<<<dim3(8, 512), 256, 0, stream>>>(GA, BW, be, br, bh, out);
    rnn_local<<<dim3(256), dim3(512), 0, stream>>>(WhT, out, need);
}